// Round 13
// baseline (141.973 us; speedup 1.0000x reference)
//
#include <hip/hip_runtime.h>
#include <stdint.h>

#define DF 32
#define BN 256               // nodes per bucket (dst >> 8)
#define MAXB 512             // max buckets on fast path (nN <= 131072)
#define CHUNK 4096           // edges per partition WG
#define NBCB 512             // bcount blocks in fused kernel
typedef unsigned long long u64;
typedef unsigned short u16;
typedef unsigned int u32;
typedef unsigned char u8;

static __device__ __forceinline__ u16 f2bf(float x) {     // RTN-even
    unsigned u = __float_as_uint(x);
    return (u16)((u + 0x7fff + ((u >> 16) & 1)) >> 16);
}
static __device__ __forceinline__ float bf2f(u16 b) {
    return __uint_as_float((unsigned)b << 16);
}

// ======================= fused cast + partial bucket-histogram ===============
// blocks [0,NBCB): per-block partial histograms of dst>>8 (plain writes, no
// pre-zero needed). blocks [NBCB,...): f32->bf16 cast of emb.
__global__ void k_fused(const float* __restrict__ emb, u16* __restrict__ E16, int n4,
                        const int* __restrict__ dst, int nE,
                        int* __restrict__ partials, int nbuck) {
    int b = blockIdx.x;
    if (b < NBCB) {
        __shared__ int h[MAXB];
        for (int i = threadIdx.x; i < MAXB; i += blockDim.x) h[i] = 0;
        __syncthreads();
        for (int i = b * blockDim.x + threadIdx.x; i < nE; i += NBCB * blockDim.x)
            atomicAdd(&h[dst[i] >> 8], 1);
        __syncthreads();
        for (int i = threadIdx.x; i < MAXB; i += blockDim.x)
            partials[b * MAXB + i] = h[i];
    } else {
        int i = (b - NBCB) * blockDim.x + threadIdx.x;
        if (i < n4) {
            float4 v = reinterpret_cast<const float4*>(emb)[i];
            ushort4 o;
            o.x = f2bf(v.x); o.y = f2bf(v.y); o.z = f2bf(v.z); o.w = f2bf(v.w);
            reinterpret_cast<ushort4*>(E16)[i] = o;
        }
    }
}

// column-sum the partials then exclusive-scan (one MAXB-thread WG)
__global__ void k_bscan2(const int* __restrict__ partials, int* __restrict__ bptr,
                         int* __restrict__ bcur, int nbuck) {
    __shared__ int a[MAXB], bsh[MAXB];
    int t = threadIdx.x;
    int v = 0;
    for (int r = 0; r < NBCB; r++) v += partials[r * MAXB + t];   // coalesced rows
    a[t] = v;
    __syncthreads();
    int* pin = a; int* pout = bsh;
    for (int off = 1; off < MAXB; off <<= 1) {
        pout[t] = pin[t] + ((t >= off) ? pin[t - off] : 0);
        __syncthreads();
        int* tmp = pin; pin = pout; pout = tmp;
    }
    int inc = pin[t];
    if (t < nbuck) { bptr[t] = inc - v; bcur[t] = inc - v; }
    if (t == nbuck - 1) bptr[nbuck] = inc;
}

// ======================= bucket partition (u32 records) ======================
// rec32 = wbits15<<17 | src (17b)  ;  ld8 = dst & 255
__global__ __launch_bounds__(512)
void k_bpart(const int* __restrict__ src, const int* __restrict__ dst,
             const float* __restrict__ w, int* __restrict__ bcur,
             u32* __restrict__ rec_g, u8* __restrict__ ld_g, int nE, int nbuck) {
    __shared__ u32 rec[CHUNK];
    __shared__ u8  ldl[CHUNK];
    __shared__ unsigned short rb[CHUNK];
    __shared__ int hist[MAXB], sa[MAXB], sb[MAXB], goff[MAXB], cur[MAXB];
    int t = threadIdx.x;
    int base = blockIdx.x * CHUNK;
    int cnt = min(CHUNK, nE - base);

    hist[t] = 0;
    __syncthreads();

    int myb[8]; u32 myrec[8]; u8 myld[8];
#pragma unroll
    for (int j = 0; j < 8; j++) {
        int i = t + j * 512;
        if (i < cnt) {
            int d = dst[base + i];
            myb[j] = d >> 8;
            u32 wbits = f2bf(w[base + i]) & 0x7fffu;   // w>=0: drop sign, bf16
            myrec[j] = (wbits << 17) | (u32)src[base + i];
            myld[j] = (u8)(d & (BN - 1));
            atomicAdd(&hist[myb[j]], 1);
        } else myb[j] = -1;
    }
    __syncthreads();

    int v = hist[t];
    sa[t] = v;
    __syncthreads();
    int* pin = sa; int* pout = sb;
    for (int off = 1; off < MAXB; off <<= 1) {
        pout[t] = pin[t] + ((t >= off) ? pin[t - off] : 0);
        __syncthreads();
        int* tmp = pin; pin = pout; pout = tmp;
    }
    int excl = pin[t] - v;
    cur[t] = excl;
    int g = 0;
    if (t < nbuck && v > 0) g = atomicAdd(&bcur[t], v);
    goff[t] = g - excl;
    __syncthreads();

#pragma unroll
    for (int j = 0; j < 8; j++) {
        if (myb[j] >= 0) {
            int p = atomicAdd(&cur[myb[j]], 1);
            rec[p] = myrec[j];
            ldl[p] = myld[j];
            rb[p] = (unsigned short)myb[j];
        }
    }
    __syncthreads();

    for (int r = t; r < cnt; r += 512) {          // bin-major -> coalesced
        int pos = goff[rb[r]] + r;
        rec_g[pos] = rec[r];
        ld_g[pos]  = ldl[r];
    }
}

// one WG per bucket: exact CSR; packed value is the record itself.
__global__ __launch_bounds__(512)
void k_csr(const int* __restrict__ bptr, const u32* __restrict__ rec_g,
           const u8* __restrict__ ld_g, int* __restrict__ rowptr,
           u32* __restrict__ packed, int nN, int nbuck) {
    __shared__ int cnt[BN], excl[BN];
    int b = blockIdx.x;
    int t = threadIdx.x;
    int s0 = bptr[b], s1 = bptr[b + 1];
    if (t < BN) cnt[t] = 0;
    __syncthreads();
    for (int i = s0 + t; i < s1; i += 512)
        atomicAdd(&cnt[ld_g[i]], 1);
    __syncthreads();
    if (t < BN) excl[t] = cnt[t];
    __syncthreads();
    for (int off = 1; off < BN; off <<= 1) {
        int u = 0;
        if (t < BN && t >= off) u = excl[t - off];
        __syncthreads();
        if (t < BN) excl[t] += u;
        __syncthreads();
    }
    int nodeBase = b * BN;
    if (t < BN) {
        int e = excl[t] - cnt[t];
        if (nodeBase + t < nN) rowptr[nodeBase + t] = s0 + e;
        cnt[t] = e;
    }
    if (b == nbuck - 1 && t == 0) rowptr[nN] = s1;
    __syncthreads();
    for (int i = s0 + t; i < s1; i += 512) {
        int ld = ld_g[i];
        int pos = s0 + atomicAdd(&cnt[ld], 1);
        packed[pos] = rec_g[i];
    }
}

// ======================= pull SpMM (16-lane groups, pipelined) ===============
// Unchanged from R12 (proven). 16 lanes per node; lane g owns features
// {2g,2g+1} as one u32 (2xbf16). packed: wbits15<<17 | src.
__global__ void k_pull(const int* __restrict__ rowptr, const u32* __restrict__ packed,
                       const u32* __restrict__ h32, u32* __restrict__ hn32, int n) {
    int gid = blockIdx.x * blockDim.x + threadIdx.x;
    int node = gid >> 4;
    int g = gid & 15;
    if (node >= n) return;
    int s0 = rowptr[node], s1 = rowptr[node + 1];
    float al0 = 0.f, ah0 = 0.f, al1 = 0.f, ah1 = 0.f,
          al2 = 0.f, ah2 = 0.f, al3 = 0.f, ah3 = 0.f;
    int nb = (s1 - s0) >> 2;
    int i = s0;
    if (nb > 0) {
        u32 q0 = packed[i], q1 = packed[i + 1], q2 = packed[i + 2], q3 = packed[i + 3];
        for (int b = 1; b < nb; b++) {
            int j = s0 + b * 4;
            u32 r0 = packed[j], r1 = packed[j + 1],          // prefetch next batch
                r2 = packed[j + 2], r3 = packed[j + 3];
            u32 v0 = h32[(size_t)(q0 & 0x1ffffu) * 16 + g];
            u32 v1 = h32[(size_t)(q1 & 0x1ffffu) * 16 + g];
            u32 v2 = h32[(size_t)(q2 & 0x1ffffu) * 16 + g];
            u32 v3 = h32[(size_t)(q3 & 0x1ffffu) * 16 + g];
            float w0 = __uint_as_float((q0 >> 17) << 16);
            float w1 = __uint_as_float((q1 >> 17) << 16);
            float w2 = __uint_as_float((q2 >> 17) << 16);
            float w3 = __uint_as_float((q3 >> 17) << 16);
            al0 += w0 * bf2f((u16)(v0 & 0xffff)); ah0 += w0 * bf2f((u16)(v0 >> 16));
            al1 += w1 * bf2f((u16)(v1 & 0xffff)); ah1 += w1 * bf2f((u16)(v1 >> 16));
            al2 += w2 * bf2f((u16)(v2 & 0xffff)); ah2 += w2 * bf2f((u16)(v2 >> 16));
            al3 += w3 * bf2f((u16)(v3 & 0xffff)); ah3 += w3 * bf2f((u16)(v3 >> 16));
            q0 = r0; q1 = r1; q2 = r2; q3 = r3;
        }
        u32 v0 = h32[(size_t)(q0 & 0x1ffffu) * 16 + g];
        u32 v1 = h32[(size_t)(q1 & 0x1ffffu) * 16 + g];
        u32 v2 = h32[(size_t)(q2 & 0x1ffffu) * 16 + g];
        u32 v3 = h32[(size_t)(q3 & 0x1ffffu) * 16 + g];
        float w0 = __uint_as_float((q0 >> 17) << 16);
        float w1 = __uint_as_float((q1 >> 17) << 16);
        float w2 = __uint_as_float((q2 >> 17) << 16);
        float w3 = __uint_as_float((q3 >> 17) << 16);
        al0 += w0 * bf2f((u16)(v0 & 0xffff)); ah0 += w0 * bf2f((u16)(v0 >> 16));
        al1 += w1 * bf2f((u16)(v1 & 0xffff)); ah1 += w1 * bf2f((u16)(v1 >> 16));
        al2 += w2 * bf2f((u16)(v2 & 0xffff)); ah2 += w2 * bf2f((u16)(v2 >> 16));
        al3 += w3 * bf2f((u16)(v3 & 0xffff)); ah3 += w3 * bf2f((u16)(v3 >> 16));
        i = s0 + nb * 4;
    }
    for (; i < s1; i++) {
        u32 p = packed[i];
        u32 v = h32[(size_t)(p & 0x1ffffu) * 16 + g];
        float wt = __uint_as_float((p >> 17) << 16);
        al0 += wt * bf2f((u16)(v & 0xffff));
        ah0 += wt * bf2f((u16)(v >> 16));
    }
    float accL = (al0 + al1) + (al2 + al3);
    float accH = (ah0 + ah1) + (ah2 + ah3);
    hn32[(size_t)node * 16 + g] = (u32)f2bf(accL) | ((u32)f2bf(accH) << 16);
}

// out = (emb + h1 + h2 + h3) * 0.25   — pure streaming
__global__ void k_final(const float* __restrict__ emb, const u32* __restrict__ h1,
                        const u32* __restrict__ h2, const u32* __restrict__ h3,
                        float* __restrict__ out, int n32) {
    int i = blockIdx.x * blockDim.x + threadIdx.x;
    if (i >= n32) return;
    float2 e = reinterpret_cast<const float2*>(emb)[i];
    u32 a = h1[i], b = h2[i], c = h3[i];
    float2 r;
    r.x = (e.x + bf2f((u16)(a & 0xffff)) + bf2f((u16)(b & 0xffff))
               + bf2f((u16)(c & 0xffff))) * 0.25f;
    r.y = (e.y + bf2f((u16)(a >> 16)) + bf2f((u16)(b >> 16))
               + bf2f((u16)(c >> 16))) * 0.25f;
    reinterpret_cast<float2*>(out)[i] = r;
}

// ======================= fallback (R1 atomic path, f32) =======================

__global__ void spmm_scatter(const int* __restrict__ src, const int* __restrict__ dst,
                             const float* __restrict__ w, const float* __restrict__ h,
                             float* __restrict__ hn, int nE) {
    int i = blockIdx.x * blockDim.x + threadIdx.x;
    int total = nE * 8;
    if (i >= total) return;
    int e = i >> 3, g = i & 7;
    int s = src[e], t = dst[e];
    float wt = w[e];
    float4 v = reinterpret_cast<const float4*>(h)[(size_t)s * 8 + g];
    float* p = hn + (size_t)t * DF + g * 4;
    atomicAdd(p + 0, v.x * wt); atomicAdd(p + 1, v.y * wt);
    atomicAdd(p + 2, v.z * wt); atomicAdd(p + 3, v.w * wt);
}
__global__ void accum_first(const float* __restrict__ emb, const float* __restrict__ hn,
                            float* __restrict__ out, int n4) {
    int i = blockIdx.x * blockDim.x + threadIdx.x;
    if (i >= n4) return;
    float4 a = reinterpret_cast<const float4*>(emb)[i];
    float4 b = reinterpret_cast<const float4*>(hn)[i];
    reinterpret_cast<float4*>(out)[i] = make_float4(a.x+b.x, a.y+b.y, a.z+b.z, a.w+b.w);
}
__global__ void accum_mid(const float* __restrict__ hn, float* __restrict__ out, int n4) {
    int i = blockIdx.x * blockDim.x + threadIdx.x;
    if (i >= n4) return;
    float4 a = reinterpret_cast<float4*>(out)[i];
    float4 b = reinterpret_cast<const float4*>(hn)[i];
    reinterpret_cast<float4*>(out)[i] = make_float4(a.x+b.x, a.y+b.y, a.z+b.z, a.w+b.w);
}
__global__ void accum_last(const float* __restrict__ hn, float* __restrict__ out, int n4) {
    int i = blockIdx.x * blockDim.x + threadIdx.x;
    if (i >= n4) return;
    float4 a = reinterpret_cast<float4*>(out)[i];
    float4 b = reinterpret_cast<const float4*>(hn)[i];
    reinterpret_cast<float4*>(out)[i] = make_float4((a.x+b.x)*0.25f, (a.y+b.y)*0.25f,
                                                    (a.z+b.z)*0.25f, (a.w+b.w)*0.25f);
}

// ======================= launch =======================

extern "C" void kernel_launch(void* const* d_in, const int* in_sizes, int n_in,
                              void* d_out, int out_size, void* d_ws, size_t ws_size,
                              hipStream_t stream) {
    const float* emb = (const float*)d_in[0];
    const int*   src = (const int*)d_in[1];
    const int*   dst = (const int*)d_in[2];
    const float* w   = (const float*)d_in[3];
    float* out = (float*)d_out;

    const int nN = in_sizes[0] / DF;
    const int nE = in_sizes[1];
    const int nbuck = (nN + BN - 1) / BN;
    const size_t hbytes  = (size_t)nN * DF * sizeof(float);   // f32 matrix
    const size_t h16b    = (size_t)nN * DF * 2;               // bf16 matrix

    char* ws = (char*)d_ws;
    // fast-path layout: E16 | H1 H2 H3 | packed | rowptr | partials | counters
    // rec32_g + ld8_g (nE*5 B) overlap H1..H3 (dead before the pulls).
    u16* E16 = (u16*)ws;
    u16* H1  = (u16*)(ws + h16b);
    u16* H2  = (u16*)(ws + 2 * h16b);
    u16* H3  = (u16*)(ws + 3 * h16b);
    u32* rec32 = (u32*)(ws + h16b);
    u8*  ld8   = (u8*)(ws + h16b + (((size_t)nE * 4 + 63) / 64) * 64);
    size_t prep = (((size_t)nE * 5 + 127) / 64) * 64;
    size_t off_pk = h16b + (prep > 3 * h16b ? prep : 3 * h16b);
    u32* packed = (u32*)(ws + off_pk);
    size_t roff = off_pk + (((size_t)nE * 4 + 63) / 64) * 64;
    int* rowptr = (int*)(ws + roff);
    size_t poff = roff + (((size_t)(nN + 1) * 4 + 63) / 64) * 64;
    int* partials = (int*)(ws + poff);
    size_t boff = poff + (size_t)NBCB * MAXB * 4;
    int* bptr = (int*)(ws + boff);
    int* bcur = bptr + MAXB + 1;
    const size_t need = boff + (size_t)(2 * MAXB + 2) * 4;

    const dim3 blk(256);

    if (nbuck <= MAXB && nN <= (1 << 17) && ws_size >= need) {
        const int n4 = nN * DF / 4;
        const int n32 = nN * 16;
        k_fused<<<NBCB + (n4 + 255) / 256, blk, 0, stream>>>(emb, E16, n4, dst, nE,
                                                             partials, nbuck);
        k_bscan2<<<1, MAXB, 0, stream>>>(partials, bptr, bcur, nbuck);
        k_bpart<<<(nE + CHUNK - 1) / CHUNK, 512, 0, stream>>>(src, dst, w, bcur,
                                                              rec32, ld8, nE, nbuck);
        k_csr<<<nbuck, 512, 0, stream>>>(bptr, rec32, ld8, rowptr, packed, nN, nbuck);

        const int pgrid = (nN * 16 + 255) / 256;
        k_pull<<<pgrid, blk, 0, stream>>>(rowptr, packed, (u32*)E16, (u32*)H1, nN);
        k_pull<<<pgrid, blk, 0, stream>>>(rowptr, packed, (u32*)H1, (u32*)H2, nN);
        k_pull<<<pgrid, blk, 0, stream>>>(rowptr, packed, (u32*)H2, (u32*)H3, nN);
        k_final<<<(n32 + 255) / 256, blk, 0, stream>>>(emb, (u32*)H1, (u32*)H2,
                                                       (u32*)H3, out, n32);
    } else {
        float* A = (float*)ws;
        float* B = (float*)(ws + hbytes);
        const int n4 = nN * DF / 4;
        const int sgrid = (nE * 8 + 255) / 256;
        const int agrid = (n4 + 255) / 256;
        hipMemsetAsync(B, 0, hbytes, stream);
        spmm_scatter<<<sgrid, blk, 0, stream>>>(src, dst, w, emb, B, nE);
        accum_first<<<agrid, blk, 0, stream>>>(emb, B, out, n4);
        hipMemsetAsync(A, 0, hbytes, stream);
        spmm_scatter<<<sgrid, blk, 0, stream>>>(src, dst, w, B, A, nE);
        accum_mid<<<agrid, blk, 0, stream>>>(A, out, n4);
        hipMemsetAsync(B, 0, hbytes, stream);
        spmm_scatter<<<sgrid, blk, 0, stream>>>(src, dst, w, A, B, nE);
        accum_last<<<agrid, blk, 0, stream>>>(B, out, n4);
    }
}

// Round 14
// 138.174 us; speedup vs baseline: 1.0275x; 1.0275x over previous
//
#include <hip/hip_runtime.h>
#include <stdint.h>

#define DF 32
#define BN 256               // nodes per bucket (dst >> 8)
#define MAXB 512             // max buckets on fast path (nN <= 131072)
#define CHUNK 4096           // edges per partition WG
typedef unsigned long long u64;
typedef unsigned short u16;
typedef unsigned int u32;

static __device__ __forceinline__ u16 f2bf(float x) {     // RTN-even
    unsigned u = __float_as_uint(x);
    return (u16)((u + 0x7fff + ((u >> 16) & 1)) >> 16);
}
static __device__ __forceinline__ float bf2f(u16 b) {
    return __uint_as_float((unsigned)b << 16);
}

// ======================= bucket partition prepass =======================

__global__ void k_bcount(const int* __restrict__ dst, int* __restrict__ bcnt,
                         int nE, int nbuck) {
    __shared__ int h[MAXB];
    for (int i = threadIdx.x; i < MAXB; i += blockDim.x) h[i] = 0;
    __syncthreads();
    for (int i = blockIdx.x * blockDim.x + threadIdx.x; i < nE;
         i += gridDim.x * blockDim.x)
        atomicAdd(&h[dst[i] >> 8], 1);
    __syncthreads();
    for (int i = threadIdx.x; i < nbuck; i += blockDim.x)
        if (h[i]) atomicAdd(&bcnt[i], h[i]);
}

__global__ void k_bscan(const int* __restrict__ bcnt, int* __restrict__ bptr,
                        int* __restrict__ bcur, int nbuck) {
    __shared__ int a[MAXB], b[MAXB];
    int t = threadIdx.x;
    int v = (t < nbuck) ? bcnt[t] : 0;
    a[t] = v;
    __syncthreads();
    int* pin = a; int* pout = b;
    for (int off = 1; off < MAXB; off <<= 1) {
        pout[t] = pin[t] + ((t >= off) ? pin[t - off] : 0);
        __syncthreads();
        int* tmp = pin; pin = pout; pout = tmp;
    }
    int inc = pin[t];
    if (t < nbuck) { bptr[t] = inc - v; bcur[t] = inc - v; }
    if (t == nbuck - 1) bptr[nbuck] = inc;
}

// record = wbits15<<25 | src<<8 | localDst  (src needs <= 17 bits)
__global__ __launch_bounds__(512)
void k_bpart(const int* __restrict__ src, const int* __restrict__ dst,
             const float* __restrict__ w, int* __restrict__ bcur,
             u64* __restrict__ rec_g, int nE, int nbuck) {
    __shared__ u64 rec[CHUNK];
    __shared__ unsigned short rb[CHUNK];
    __shared__ int hist[MAXB], sa[MAXB], sb[MAXB], goff[MAXB], cur[MAXB];
    int t = threadIdx.x;
    int base = blockIdx.x * CHUNK;
    int cnt = min(CHUNK, nE - base);

    hist[t] = 0;
    __syncthreads();

    int myb[8]; u64 myrec[8];
#pragma unroll
    for (int j = 0; j < 8; j++) {
        int i = t + j * 512;
        if (i < cnt) {
            int d = dst[base + i];
            myb[j] = d >> 8;
            u32 wbits = f2bf(w[base + i]) & 0x7fffu;   // w>=0: drop sign, bf16
            myrec[j] = ((u64)wbits << 25)
                     | ((u64)(unsigned)src[base + i] << 8)
                     | (u64)(d & (BN - 1));
            atomicAdd(&hist[myb[j]], 1);
        } else myb[j] = -1;
    }
    __syncthreads();

    int v = hist[t];
    sa[t] = v;
    __syncthreads();
    int* pin = sa; int* pout = sb;
    for (int off = 1; off < MAXB; off <<= 1) {
        pout[t] = pin[t] + ((t >= off) ? pin[t - off] : 0);
        __syncthreads();
        int* tmp = pin; pin = pout; pout = tmp;
    }
    int excl = pin[t] - v;
    cur[t] = excl;
    int g = 0;
    if (t < nbuck && v > 0) g = atomicAdd(&bcur[t], v);
    goff[t] = g - excl;
    __syncthreads();

#pragma unroll
    for (int j = 0; j < 8; j++) {
        if (myb[j] >= 0) {
            int p = atomicAdd(&cur[myb[j]], 1);
            rec[p] = myrec[j];
            rb[p] = (unsigned short)myb[j];
        }
    }
    __syncthreads();

    for (int r = t; r < cnt; r += 512) {
        int bb = rb[r];
        rec_g[goff[bb] + r] = rec[r];
    }
}

// one WG per bucket: exact CSR from bucket-sorted rec_g.
// packed(u32) = wbits15<<17 | src
__global__ __launch_bounds__(512)
void k_csr(const int* __restrict__ bptr, const u64* __restrict__ rec_g,
           int* __restrict__ rowptr, u32* __restrict__ packed, int nN, int nbuck) {
    __shared__ int cnt[BN], excl[BN];
    int b = blockIdx.x;
    int t = threadIdx.x;
    int s0 = bptr[b], s1 = bptr[b + 1];
    if (t < BN) cnt[t] = 0;
    __syncthreads();
    for (int i = s0 + t; i < s1; i += 512)
        atomicAdd(&cnt[(int)(rec_g[i] & (BN - 1))], 1);
    __syncthreads();
    if (t < BN) excl[t] = cnt[t];
    __syncthreads();
    for (int off = 1; off < BN; off <<= 1) {
        int u = 0;
        if (t < BN && t >= off) u = excl[t - off];
        __syncthreads();
        if (t < BN) excl[t] += u;
        __syncthreads();
    }
    int nodeBase = b * BN;
    if (t < BN) {
        int e = excl[t] - cnt[t];
        if (nodeBase + t < nN) rowptr[nodeBase + t] = s0 + e;
        cnt[t] = e;
    }
    if (b == nbuck - 1 && t == 0) rowptr[nN] = s1;
    __syncthreads();
    for (int i = s0 + t; i < s1; i += 512) {
        u64 r = rec_g[i];
        int ld = (int)(r & (BN - 1));
        int pos = s0 + atomicAdd(&cnt[ld], 1);
        packed[pos] = (u32)(((r >> 25) & 0x7fffull) << 17) | (u32)((r >> 8) & 0x1ffffull);
    }
}

// f32 -> bf16 cast (4 elems/thread) + fused bcnt zeroing
__global__ void k_cast(const float* __restrict__ x, u16* __restrict__ y, int n4,
                       int* __restrict__ bcnt) {
    int i = blockIdx.x * blockDim.x + threadIdx.x;
    if (i < MAXB) bcnt[i] = 0;
    if (i >= n4) return;
    float4 v = reinterpret_cast<const float4*>(x)[i];
    ushort4 o;
    o.x = f2bf(v.x); o.y = f2bf(v.y); o.z = f2bf(v.z); o.w = f2bf(v.w);
    reinterpret_cast<ushort4*>(y)[i] = o;
}

// ======================= pull SpMM (16-lane groups, pipelined) ===============
// 16 lanes per node; lane g owns features {2g, 2g+1} as one u32 (2xbf16).
// packed is u32: wbits15<<17 | src. Batch b+1's packed records prefetch while
// batch b's gathers are in flight (removes packed L2-hit latency from the
// dependent chain). 256-thread blocks (proven best occupancy config).
__global__ void k_pull(const int* __restrict__ rowptr, const u32* __restrict__ packed,
                       const u32* __restrict__ h32, u32* __restrict__ hn32, int n) {
    int gid = blockIdx.x * blockDim.x + threadIdx.x;
    int node = gid >> 4;
    int g = gid & 15;
    if (node >= n) return;
    int s0 = rowptr[node], s1 = rowptr[node + 1];
    float al0 = 0.f, ah0 = 0.f, al1 = 0.f, ah1 = 0.f,
          al2 = 0.f, ah2 = 0.f, al3 = 0.f, ah3 = 0.f;
    int nb = (s1 - s0) >> 2;
    int i = s0;
    if (nb > 0) {
        u32 q0 = packed[i], q1 = packed[i + 1], q2 = packed[i + 2], q3 = packed[i + 3];
        for (int b = 1; b < nb; b++) {
            int j = s0 + b * 4;
            u32 r0 = packed[j], r1 = packed[j + 1],          // prefetch next batch
                r2 = packed[j + 2], r3 = packed[j + 3];
            u32 v0 = h32[(size_t)(q0 & 0x1ffffu) * 16 + g];
            u32 v1 = h32[(size_t)(q1 & 0x1ffffu) * 16 + g];
            u32 v2 = h32[(size_t)(q2 & 0x1ffffu) * 16 + g];
            u32 v3 = h32[(size_t)(q3 & 0x1ffffu) * 16 + g];
            float w0 = __uint_as_float((q0 >> 17) << 16);
            float w1 = __uint_as_float((q1 >> 17) << 16);
            float w2 = __uint_as_float((q2 >> 17) << 16);
            float w3 = __uint_as_float((q3 >> 17) << 16);
            al0 += w0 * bf2f((u16)(v0 & 0xffff)); ah0 += w0 * bf2f((u16)(v0 >> 16));
            al1 += w1 * bf2f((u16)(v1 & 0xffff)); ah1 += w1 * bf2f((u16)(v1 >> 16));
            al2 += w2 * bf2f((u16)(v2 & 0xffff)); ah2 += w2 * bf2f((u16)(v2 >> 16));
            al3 += w3 * bf2f((u16)(v3 & 0xffff)); ah3 += w3 * bf2f((u16)(v3 >> 16));
            q0 = r0; q1 = r1; q2 = r2; q3 = r3;
        }
        u32 v0 = h32[(size_t)(q0 & 0x1ffffu) * 16 + g];
        u32 v1 = h32[(size_t)(q1 & 0x1ffffu) * 16 + g];
        u32 v2 = h32[(size_t)(q2 & 0x1ffffu) * 16 + g];
        u32 v3 = h32[(size_t)(q3 & 0x1ffffu) * 16 + g];
        float w0 = __uint_as_float((q0 >> 17) << 16);
        float w1 = __uint_as_float((q1 >> 17) << 16);
        float w2 = __uint_as_float((q2 >> 17) << 16);
        float w3 = __uint_as_float((q3 >> 17) << 16);
        al0 += w0 * bf2f((u16)(v0 & 0xffff)); ah0 += w0 * bf2f((u16)(v0 >> 16));
        al1 += w1 * bf2f((u16)(v1 & 0xffff)); ah1 += w1 * bf2f((u16)(v1 >> 16));
        al2 += w2 * bf2f((u16)(v2 & 0xffff)); ah2 += w2 * bf2f((u16)(v2 >> 16));
        al3 += w3 * bf2f((u16)(v3 & 0xffff)); ah3 += w3 * bf2f((u16)(v3 >> 16));
        i = s0 + nb * 4;
    }
    for (; i < s1; i++) {
        u32 p = packed[i];
        u32 v = h32[(size_t)(p & 0x1ffffu) * 16 + g];
        float wt = __uint_as_float((p >> 17) << 16);
        al0 += wt * bf2f((u16)(v & 0xffff));
        ah0 += wt * bf2f((u16)(v >> 16));
    }
    float accL = (al0 + al1) + (al2 + al3);
    float accH = (ah0 + ah1) + (ah2 + ah3);
    hn32[(size_t)node * 16 + g] = (u32)f2bf(accL) | ((u32)f2bf(accH) << 16);
}

// out = (emb + h1 + h2 + h3) * 0.25   — pure streaming
__global__ void k_final(const float* __restrict__ emb, const u32* __restrict__ h1,
                        const u32* __restrict__ h2, const u32* __restrict__ h3,
                        float* __restrict__ out, int n32) {
    int i = blockIdx.x * blockDim.x + threadIdx.x;
    if (i >= n32) return;
    float2 e = reinterpret_cast<const float2*>(emb)[i];
    u32 a = h1[i], b = h2[i], c = h3[i];
    float2 r;
    r.x = (e.x + bf2f((u16)(a & 0xffff)) + bf2f((u16)(b & 0xffff))
               + bf2f((u16)(c & 0xffff))) * 0.25f;
    r.y = (e.y + bf2f((u16)(a >> 16)) + bf2f((u16)(b >> 16))
               + bf2f((u16)(c >> 16))) * 0.25f;
    reinterpret_cast<float2*>(out)[i] = r;
}

// ======================= fallback (R1 atomic path, f32) =======================

__global__ void spmm_scatter(const int* __restrict__ src, const int* __restrict__ dst,
                             const float* __restrict__ w, const float* __restrict__ h,
                             float* __restrict__ hn, int nE) {
    int i = blockIdx.x * blockDim.x + threadIdx.x;
    int total = nE * 8;
    if (i >= total) return;
    int e = i >> 3, g = i & 7;
    int s = src[e], t = dst[e];
    float wt = w[e];
    float4 v = reinterpret_cast<const float4*>(h)[(size_t)s * 8 + g];
    float* p = hn + (size_t)t * DF + g * 4;
    atomicAdd(p + 0, v.x * wt); atomicAdd(p + 1, v.y * wt);
    atomicAdd(p + 2, v.z * wt); atomicAdd(p + 3, v.w * wt);
}
__global__ void accum_first(const float* __restrict__ emb, const float* __restrict__ hn,
                            float* __restrict__ out, int n4) {
    int i = blockIdx.x * blockDim.x + threadIdx.x;
    if (i >= n4) return;
    float4 a = reinterpret_cast<const float4*>(emb)[i];
    float4 b = reinterpret_cast<const float4*>(hn)[i];
    reinterpret_cast<float4*>(out)[i] = make_float4(a.x+b.x, a.y+b.y, a.z+b.z, a.w+b.w);
}
__global__ void accum_mid(const float* __restrict__ hn, float* __restrict__ out, int n4) {
    int i = blockIdx.x * blockDim.x + threadIdx.x;
    if (i >= n4) return;
    float4 a = reinterpret_cast<float4*>(out)[i];
    float4 b = reinterpret_cast<const float4*>(hn)[i];
    reinterpret_cast<float4*>(out)[i] = make_float4(a.x+b.x, a.y+b.y, a.z+b.z, a.w+b.w);
}
__global__ void accum_last(const float* __restrict__ hn, float* __restrict__ out, int n4) {
    int i = blockIdx.x * blockDim.x + threadIdx.x;
    if (i >= n4) return;
    float4 a = reinterpret_cast<float4*>(out)[i];
    float4 b = reinterpret_cast<const float4*>(hn)[i];
    reinterpret_cast<float4*>(out)[i] = make_float4((a.x+b.x)*0.25f, (a.y+b.y)*0.25f,
                                                    (a.z+b.z)*0.25f, (a.w+b.w)*0.25f);
}

// ======================= launch =======================

extern "C" void kernel_launch(void* const* d_in, const int* in_sizes, int n_in,
                              void* d_out, int out_size, void* d_ws, size_t ws_size,
                              hipStream_t stream) {
    const float* emb = (const float*)d_in[0];
    const int*   src = (const int*)d_in[1];
    const int*   dst = (const int*)d_in[2];
    const float* w   = (const float*)d_in[3];
    float* out = (float*)d_out;

    const int nN = in_sizes[0] / DF;
    const int nE = in_sizes[1];
    const int nbuck = (nN + BN - 1) / BN;
    const size_t hbytes  = (size_t)nN * DF * sizeof(float);   // f32 matrix
    const size_t h16b    = (size_t)nN * DF * 2;               // bf16 matrix

    char* ws = (char*)d_ws;
    // fast-path layout: E16 | H1 | H2 | H3 | packed | rowptr | counters
    // rec_g (nE*8 B) overlaps H1..H3 (dead before the pulls write them).
    u16* E16 = (u16*)ws;
    u16* H1  = (u16*)(ws + h16b);
    u16* H2  = (u16*)(ws + 2 * h16b);
    u16* H3  = (u16*)(ws + 3 * h16b);
    u64* rec_g = (u64*)(ws + h16b);
    size_t recb = (((size_t)nE * 8 + 63) / 64) * 64;
    size_t off_pk = h16b + (recb > 3 * h16b ? recb : 3 * h16b);
    u32* packed = (u32*)(ws + off_pk);
    size_t roff = off_pk + (((size_t)nE * 4 + 63) / 64) * 64;
    int* rowptr = (int*)(ws + roff);
    size_t boff = roff + (((size_t)(nN + 1) * 4 + 63) / 64) * 64;
    int* bcnt = (int*)(ws + boff);
    int* bptr = bcnt + MAXB;
    int* bcur = bptr + MAXB + 1;
    const size_t need = boff + (size_t)(3 * MAXB + 1) * 4;

    const dim3 blk(256);

    if (nbuck <= MAXB && nN <= (1 << 17) && ws_size >= need) {
        const int n4 = nN * DF / 4;
        const int n32 = nN * 16;
        k_cast<<<(n4 + 255) / 256, blk, 0, stream>>>(emb, E16, n4, bcnt);
        k_bcount<<<512, blk, 0, stream>>>(dst, bcnt, nE, nbuck);
        k_bscan<<<1, MAXB, 0, stream>>>(bcnt, bptr, bcur, nbuck);
        k_bpart<<<(nE + CHUNK - 1) / CHUNK, 512, 0, stream>>>(src, dst, w, bcur,
                                                              rec_g, nE, nbuck);
        k_csr<<<nbuck, 512, 0, stream>>>(bptr, rec_g, rowptr, packed, nN, nbuck);

        const int pgrid = (nN * 16 + 255) / 256;
        k_pull<<<pgrid, blk, 0, stream>>>(rowptr, packed, (u32*)E16, (u32*)H1, nN);
        k_pull<<<pgrid, blk, 0, stream>>>(rowptr, packed, (u32*)H1, (u32*)H2, nN);
        k_pull<<<pgrid, blk, 0, stream>>>(rowptr, packed, (u32*)H2, (u32*)H3, nN);
        k_final<<<(n32 + 255) / 256, blk, 0, stream>>>(emb, (u32*)H1, (u32*)H2,
                                                       (u32*)H3, out, n32);
    } else {
        float* A = (float*)ws;
        float* B = (float*)(ws + hbytes);
        const int n4 = nN * DF / 4;
        const int sgrid = (nE * 8 + 255) / 256;
        const int agrid = (n4 + 255) / 256;
        hipMemsetAsync(B, 0, hbytes, stream);
        spmm_scatter<<<sgrid, blk, 0, stream>>>(src, dst, w, emb, B, nE);
        accum_first<<<agrid, blk, 0, stream>>>(emb, B, out, n4);
        hipMemsetAsync(A, 0, hbytes, stream);
        spmm_scatter<<<sgrid, blk, 0, stream>>>(src, dst, w, B, A, nE);
        accum_mid<<<agrid, blk, 0, stream>>>(A, out, n4);
        hipMemsetAsync(B, 0, hbytes, stream);
        spmm_scatter<<<sgrid, blk, 0, stream>>>(src, dst, w, A, B, nE);
        accum_last<<<agrid, blk, 0, stream>>>(B, out, n4);
    }
}